// Round 4
// baseline (20050.377 us; speedup 1.0000x reference)
//
#include <hip/hip_runtime.h>
#include <math.h>

#define B_  64
#define N_  512
#define H_  1024
#define NH_ 8
#define HD_ 128
#define S_  24
#define NBLK 256

struct Params {
  const float *enc, *h0, *c0, *x0;
  const float *W_ih, *b_ih, *W_hh, *b_hh;
  const float *Wqkv, *bqkv, *Wout, *bout, *Wqt, *bqt;
  float *P, *hbuf, *cbuf, *hq, *ctx, *xbuf, *Kc, *Vc;
  float *logits, *idx;
};

// ---------------------------------------------------------------------------
// Hand-rolled grid barrier: sense-reversing, agent-scope atomics.
// Generation-based -> robust to whatever values persist across launches
// (counter always returns to 0 at barrier exit; gen just keeps counting).
// __threadfence() gives the cross-XCD L2 writeback/invalidate (G16).
// ---------------------------------------------------------------------------
__device__ unsigned g_bar_count = 0;
__device__ unsigned g_bar_gen = 0;

__device__ __forceinline__ void gbar()
{
  __syncthreads();                 // drains this block's vmcnt (stores done)
  if (threadIdx.x == 0) {
    __threadfence();               // make our writes visible device-wide
    unsigned g = __hip_atomic_load(&g_bar_gen, __ATOMIC_RELAXED,
                                   __HIP_MEMORY_SCOPE_AGENT);
    unsigned a = __hip_atomic_fetch_add(&g_bar_count, 1u, __ATOMIC_ACQ_REL,
                                        __HIP_MEMORY_SCOPE_AGENT);
    if (a == NBLK - 1) {
      __hip_atomic_store(&g_bar_count, 0u, __ATOMIC_RELAXED,
                         __HIP_MEMORY_SCOPE_AGENT);
      __hip_atomic_store(&g_bar_gen, g + 1u, __ATOMIC_RELEASE,
                         __HIP_MEMORY_SCOPE_AGENT);
    } else {
      while (__hip_atomic_load(&g_bar_gen, __ATOMIC_ACQUIRE,
                               __HIP_MEMORY_SCOPE_AGENT) == g) {
        __builtin_amdgcn_s_sleep(1);
      }
    }
    __threadfence();               // invalidate stale L1/L2 before reads
  }
  __syncthreads();
}

// ---------------------------------------------------------------------------
// GEMM tile: 64 rows (batch) x 128 cols, split-K slice KS.
// 512 threads: tn=tid&31 (4 cols), tm=tid>>5 (4 rows), 16 FMA per k.
// W pre-offset to tile's first row. Pdst = P + sp*64*N + nb*128.
// ---------------------------------------------------------------------------
__device__ __forceinline__ void gemm_tile(
    const float* __restrict__ A, const float* __restrict__ W,
    int ld, int koff, int KS, float* __restrict__ Pdst, int N,
    float* As /*16x68*/, float* Bs /*16x132*/)
{
  const int tid = threadIdx.x;
  const int tn = tid & 31, tm = tid >> 5;
  const int lr = tid >> 2, lc = (tid & 3) * 4;
  float acc[4][4];
#pragma unroll
  for (int i = 0; i < 4; ++i)
#pragma unroll
    for (int j = 0; j < 4; ++j) acc[i][j] = 0.f;

  const float* Wrow = W + (size_t)lr * ld + koff + lc;   // lr 0..127
  const float* Arow = A + (size_t)lr * ld + koff + lc;   // tid<256 (lr 0..63)

  for (int k0 = 0; k0 < KS; k0 += 16) {
    float4 b4 = *(const float4*)(Wrow + k0);
    if (tid < 256) {
      float4 a4 = *(const float4*)(Arow + k0);
      As[(lc + 0) * 68 + lr] = a4.x; As[(lc + 1) * 68 + lr] = a4.y;
      As[(lc + 2) * 68 + lr] = a4.z; As[(lc + 3) * 68 + lr] = a4.w;
    }
    Bs[(lc + 0) * 132 + lr] = b4.x; Bs[(lc + 1) * 132 + lr] = b4.y;
    Bs[(lc + 2) * 132 + lr] = b4.z; Bs[(lc + 3) * 132 + lr] = b4.w;
    __syncthreads();
#pragma unroll
    for (int k = 0; k < 16; ++k) {
      float av[4], bv[4];
      *(float4*)av = *(const float4*)(As + k * 68 + tm * 4);
      *(float4*)bv = *(const float4*)(Bs + k * 132 + tn * 4);
#pragma unroll
      for (int i = 0; i < 4; ++i)
#pragma unroll
        for (int j = 0; j < 4; ++j)
          acc[i][j] = fmaf(av[i], bv[j], acc[i][j]);
    }
    __syncthreads();
  }
#pragma unroll
  for (int i = 0; i < 4; ++i)
    *(float4*)(Pdst + (size_t)(tm * 4 + i) * N + tn * 4) =
        make_float4(acc[i][0], acc[i][1], acc[i][2], acc[i][3]);
}

__device__ __forceinline__ float sigm(float x) { return 1.f / (1.f + expf(-x)); }

__device__ __forceinline__ void ins3(float v, int i,
    float& v0, int& i0, float& v1, int& i1, float& v2, int& i2)
{
  if (v > v0 || (v == v0 && i < i0)) {
    v2 = v1; i2 = i1; v1 = v0; i1 = i0; v0 = v; i0 = i;
  } else if (v > v1 || (v == v1 && i < i1)) {
    v2 = v1; i2 = i1; v1 = v; i1 = i;
  } else if (v > v2 || (v == v2 && i < i2)) {
    v2 = v; i2 = i;
  }
}

// ---------------------------------------------------------------------------
// Persistent kernel: 256 blocks x 512 threads, all 24 steps, 9 barriers/step.
// ---------------------------------------------------------------------------
__global__ __launch_bounds__(512, 2) void decoder(Params p)
{
  __shared__ float smem[3200];
  float* As = smem;            // 16*68
  float* Bs = smem + 1088;     // 16*132

  const int tid = threadIdx.x;
  const int bid = blockIdx.x;
  const int gtid = bid * 512 + tid;

  for (int t = 0; t < S_; ++t) {
    const float* xin   = t ? p.xbuf : p.x0;
    const float* hprev = t ? p.hbuf : p.h0;
    const float* cprev = t ? p.cbuf : p.c0;

    // ---- 1: gates = [x|h] @ [W_ih|W_hh]^T -> P[8][64][4096], 256 tasks
    {
      int nb = bid & 31, sp = bid >> 5;
      int ks = sp * 512;
      const float* A; const float* W; int ld, koff;
      if (ks < 3072) { A = xin;   W = p.W_ih; ld = 3072; koff = ks; }
      else           { A = hprev; W = p.W_hh; ld = 1024; koff = ks - 3072; }
      gemm_tile(A, W + (size_t)nb * 128 * ld, ld, koff, 512,
                p.P + (size_t)sp * 64 * 4096 + nb * 128, 4096, As, Bs);
    }
    gbar();

    // ---- 2: LSTM reduce + pointwise -> hbuf, cbuf
    if (gtid < 65536) {
      int b = gtid >> 10, j = gtid & 1023;
      float gv[4];
#pragma unroll
      for (int c = 0; c < 4; ++c) {
        int n = j + 1024 * c;
        float s = p.b_ih[n] + p.b_hh[n];
#pragma unroll
        for (int sp = 0; sp < 8; ++sp) s += p.P[((size_t)sp * 64 + b) * 4096 + n];
        gv[c] = s;
      }
      float c = sigm(gv[1]) * cprev[gtid] + sigm(gv[0]) * tanhf(gv[2]);
      p.cbuf[gtid] = c;
      p.hbuf[gtid] = sigm(gv[3]) * tanhf(c);
    }
    gbar();

    // ---- 3: qkv = h @ Wqkv^T -> P[8][64][3072], 192 tasks
    if (bid < 192) {
      int nb = bid % 24, sp = bid / 24;
      gemm_tile(p.hbuf, p.Wqkv + (size_t)nb * 128 * 1024, 1024, sp * 128, 128,
                p.P + (size_t)sp * 64 * 3072 + nb * 128, 3072, As, Bs);
    }
    gbar();

    // ---- 4: attention (fused qkv reduce). 128 blocks x 4 quarters.
    if (bid < 128) {
      const float scale = 0.08838834764831845f;  // 1/sqrt(128)
      int q4 = tid >> 7, d = tid & 127;
      int task = bid * 4 + q4;                   // 0..511
      int b = task >> 3, h = task & 7;
      const float* Pb = p.P + (size_t)b * 3072 + h * 128 + d;
      float qv = p.bqkv[h * 128 + d];
      float kv = p.bqkv[1024 + h * 128 + d];
      float vv = p.bqkv[2048 + h * 128 + d];
#pragma unroll
      for (int sp = 0; sp < 8; ++sp) {
        const float* pp = Pb + (size_t)sp * 64 * 3072;
        qv += pp[0]; kv += pp[1024]; vv += pp[2048];
      }
      float* Kb = p.Kc + (size_t)(b * NH_ + h) * S_ * HD_;
      float* Vb = p.Vc + (size_t)(b * NH_ + h) * S_ * HD_;
      Kb[t * 128 + d] = kv;
      Vb[t * 128 + d] = vv;
      float* qs = smem + q4 * 128;         // 4*128
      float* sc = smem + 512 + q4 * 24;    // 4*24
      qs[d] = qv;
      __syncthreads();                      // also orders K/V row-t writes
      int wave = d >> 6, lane = d & 63;
      for (int s = wave; s <= t; s += 2) {
        float pr = qs[lane] * Kb[s * 128 + lane] + qs[lane + 64] * Kb[s * 128 + lane + 64];
#pragma unroll
        for (int off = 32; off > 0; off >>= 1) pr += __shfl_down(pr, off, 64);
        if (lane == 0) sc[s] = pr * scale;
      }
      __syncthreads();
      float m = -3.4e38f;
      for (int s = 0; s <= t; ++s) m = fmaxf(m, sc[s]);
      float den = 0.f;
      for (int s = 0; s <= t; ++s) den += expf(sc[s] - m);
      float acc = 0.f;
      for (int s = 0; s <= t; ++s) acc += expf(sc[s] - m) * Vb[s * 128 + d];
      p.ctx[(size_t)b * 1024 + h * 128 + d] = acc / den;
    }
    gbar();

    // ---- 5: attn_out = ctx @ Wout^T -> P[16][64][1024], 128 tasks
    if (bid < 128) {
      int nb = bid & 7, sp = bid >> 3;
      gemm_tile(p.ctx, p.Wout + (size_t)nb * 128 * 1024, 1024, sp * 64, 64,
                p.P + (size_t)sp * 64 * 1024 + nb * 128, 1024, As, Bs);
    }
    gbar();

    // ---- 6: hq = 0.5*(h + attn_out-reduce)
    if (gtid < 65536) {
      int b = gtid >> 10, j = gtid & 1023;
      float s = p.bout[j];
#pragma unroll
      for (int sp = 0; sp < 16; ++sp) s += p.P[((size_t)sp * 64 + b) * 1024 + j];
      p.hq[gtid] = 0.5f * (p.hbuf[gtid] + s);
    }
    gbar();

    // ---- 7: qt = hq @ Wqt^T -> P[16][64][1024], 128 tasks
    if (bid < 128) {
      int nb = bid & 7, sp = bid >> 3;
      gemm_tile(p.hq, p.Wqt + (size_t)nb * 128 * 1024, 1024, sp * 64, 64,
                p.P + (size_t)sp * 64 * 1024 + nb * 128, 1024, As, Bs);
    }
    gbar();

    // ---- 8: logits (fused qt reduce). One b per block (bid>>2), 128 n each.
    float* lo = p.logits + (size_t)t * B_ * N_;
    {
      int b = bid >> 2, ng = bid & 3;       // 128 n per block
      for (int i = tid; i < 1024; i += 512) {
        float s = p.bqt[i];
#pragma unroll
        for (int sp = 0; sp < 16; ++sp) s += p.P[((size_t)sp * 64 + b) * 1024 + i];
        smem[i] = s;
      }
      __syncthreads();
      int wave = tid >> 6, lane = tid & 63;
      for (int j = 0; j < 16; ++j) {
        int n = ng * 128 + wave * 16 + j;
        const float* e = p.enc + ((size_t)b * N_ + n) * 1024;
        float pr = 0.f;
#pragma unroll
        for (int i = 0; i < 16; ++i) pr = fmaf(smem[lane + 64 * i], e[lane + 64 * i], pr);
#pragma unroll
        for (int off = 32; off > 0; off >>= 1) pr += __shfl_down(pr, off, 64);
        if (lane == 0) lo[(size_t)b * N_ + n] = pr;
      }
    }
    gbar();

    // ---- 9: top3 + gather next x. 64 blocks.
    if (bid < 64) {
      int b = bid;
      float* sv = smem;                       // 192 floats
      int*   si = (int*)(smem + 192);         // 192 ints
      int*   topi = (int*)(smem + 384);
      const float* lrow = lo + (size_t)b * N_;
      if (tid < 64) {
        float v0 = -3.4e38f, v1 = -3.4e38f, v2 = -3.4e38f;
        int i0 = 0x7fffffff, i1 = 0x7fffffff, i2 = 0x7fffffff;
        for (int n = tid; n < N_; n += 64) ins3(lrow[n], n, v0, i0, v1, i1, v2, i2);
        sv[tid * 3 + 0] = v0; si[tid * 3 + 0] = i0;
        sv[tid * 3 + 1] = v1; si[tid * 3 + 1] = i1;
        sv[tid * 3 + 2] = v2; si[tid * 3 + 2] = i2;
      }
      __syncthreads();
      if (tid == 0) {
        float w0 = -3.4e38f, w1 = -3.4e38f, w2 = -3.4e38f;
        int j0 = 0x7fffffff, j1 = 0x7fffffff, j2 = 0x7fffffff;
        for (int k = 0; k < 192; ++k) ins3(sv[k], si[k], w0, j0, w1, j1, w2, j2);
        int a = j0, bb = j1, c = j2, tw;
        if (a > bb) { tw = a; a = bb; bb = tw; }
        if (bb > c) { tw = bb; bb = c; c = tw; }
        if (a > bb) { tw = a; a = bb; bb = tw; }
        topi[0] = a; topi[1] = bb; topi[2] = c;
        float* io = p.idx + (size_t)t * B_ * 3 + b * 3;
        io[0] = (float)a; io[1] = (float)bb; io[2] = (float)c;
      }
      __syncthreads();
      for (int r = 0; r < 3; ++r) {
        const float* e = p.enc + ((size_t)b * N_ + topi[r]) * 1024;
        for (int i = tid; i < 1024; i += 512)
          p.xbuf[(size_t)b * 3072 + r * 1024 + i] = e[i];
      }
    }
    gbar();
  }
}

// ---------------------------------------------------------------------------
extern "C" void kernel_launch(void* const* d_in, const int* in_sizes, int n_in,
                              void* d_out, int out_size, void* d_ws, size_t ws_size,
                              hipStream_t stream)
{
  (void)in_sizes; (void)n_in; (void)out_size; (void)ws_size;
  Params p;
  p.enc   = (const float*)d_in[0];
  p.h0    = (const float*)d_in[1];
  p.c0    = (const float*)d_in[2];
  p.x0    = (const float*)d_in[4];
  p.W_ih  = (const float*)d_in[6];
  p.b_ih  = (const float*)d_in[7];
  p.W_hh  = (const float*)d_in[8];
  p.b_hh  = (const float*)d_in[9];
  p.Wqkv  = (const float*)d_in[10];
  p.bqkv  = (const float*)d_in[11];
  p.Wout  = (const float*)d_in[12];
  p.bout  = (const float*)d_in[13];
  p.Wqt   = (const float*)d_in[14];
  p.bqt   = (const float*)d_in[15];

  float* ws = (float*)d_ws;
  p.P    = ws;                          // 8*64*4096 floats (phase-shared)
  p.hbuf = p.P + 8 * 64 * 4096;
  p.cbuf = p.hbuf + 64 * 1024;
  p.hq   = p.cbuf + 64 * 1024;
  p.ctx  = p.hq + 64 * 1024;
  p.xbuf = p.ctx + 64 * 1024;           // 64*3072
  p.Kc   = p.xbuf + 64 * 3072;          // 64*8*24*128
  p.Vc   = p.Kc + 64 * NH_ * S_ * HD_;

  p.logits = (float*)d_out;                       // [S,B,N]
  p.idx    = p.logits + (size_t)S_ * B_ * N_;     // [S,B,3] as float

  void* args[] = { &p };
  hipLaunchCooperativeKernel((void*)decoder, dim3(NBLK), dim3(512), args, 0, stream);
}

// Round 5
// 8653.130 us; speedup vs baseline: 2.3171x; 2.3171x over previous
//
#include <hip/hip_runtime.h>
#include <math.h>

#define B_  64
#define N_  512
#define H_  1024
#define NH_ 8
#define HD_ 128
#define S_  24
#define NBLK 256

struct Params {
  const float *enc, *h0, *c0, *x0;
  const float *W_ih, *b_ih, *W_hh, *b_hh;
  const float *Wqkv, *bqkv, *Wout, *bout, *Wqt, *bqt;
  float *P, *hbuf, *cbuf, *hq, *ctx, *xbuf, *Kc, *Vc;
  float *logits, *idx;
};

// ---------------------------------------------------------------------------
// Device-scope (agent) relaxed load/store: bypass L1/L2, coherent at the
// Infinity Cache. Used for ALL cross-block communicated data, so grid
// barriers need NO cache writeback/invalidate ops — only vmcnt drain.
// ---------------------------------------------------------------------------
__device__ __forceinline__ float dload(const float* p) {
  return __hip_atomic_load(p, __ATOMIC_RELAXED, __HIP_MEMORY_SCOPE_AGENT);
}
__device__ __forceinline__ void dstore(float* p, float v) {
  __hip_atomic_store(p, v, __ATOMIC_RELAXED, __HIP_MEMORY_SCOPE_AGENT);
}

// ---------------------------------------------------------------------------
// Grid barrier, contention-free:
//  - arrival: relaxed agent store to a per-block flag (padded to own line)
//  - block 0: 256 threads poll the 256 flags in parallel (relaxed), then
//    tid0 publishes generation word; other blocks poll it (relaxed).
//  - monotonic generation (device globals persist across graph replays;
//    wrap-safe compares; flags never need resetting).
//  - data correctness: producers drain vmcnt before arrival store; all
//    comm data is agent-scope so IC is the single coherence point.
// ---------------------------------------------------------------------------
struct PadFlag { unsigned v; unsigned pad[15]; };
__device__ PadFlag g_flags[NBLK];
__device__ unsigned g_gen = 0;

__device__ __forceinline__ void gbar(unsigned target)
{
  __syncthreads();
  asm volatile("s_waitcnt vmcnt(0) lgkmcnt(0)" ::: "memory");
  if (blockIdx.x == 0) {
    if (threadIdx.x < NBLK) {
      if (threadIdx.x == 0)
        __hip_atomic_store(&g_flags[0].v, target, __ATOMIC_RELAXED,
                           __HIP_MEMORY_SCOPE_AGENT);
      while ((int)(__hip_atomic_load(&g_flags[threadIdx.x].v, __ATOMIC_RELAXED,
                                     __HIP_MEMORY_SCOPE_AGENT) - target) < 0)
        __builtin_amdgcn_s_sleep(1);
    }
    __syncthreads();
    asm volatile("s_waitcnt vmcnt(0)" ::: "memory");
    if (threadIdx.x == 0)
      __hip_atomic_store(&g_gen, target, __ATOMIC_RELAXED,
                         __HIP_MEMORY_SCOPE_AGENT);
  } else {
    if (threadIdx.x == 0) {
      __hip_atomic_store(&g_flags[blockIdx.x].v, target, __ATOMIC_RELAXED,
                         __HIP_MEMORY_SCOPE_AGENT);
      while ((int)(__hip_atomic_load(&g_gen, __ATOMIC_RELAXED,
                                     __HIP_MEMORY_SCOPE_AGENT) - target) < 0)
        __builtin_amdgcn_s_sleep(1);
    }
    __syncthreads();
  }
}

// ---------------------------------------------------------------------------
// GEMM tile: 64 rows (batch) x 128 cols, split-K slice KS.
// 512 threads: tn=tid&31 (4 cols), tm=tid>>5 (4 rows), 16 FMA per k.
// A loaded agent-scope (comm buffer); W cached (read-only weight);
// P written agent-scope.
// ---------------------------------------------------------------------------
__device__ __forceinline__ void gemm_tile(
    const float* __restrict__ A, const float* __restrict__ W,
    int ld, int koff, int KS, float* __restrict__ Pdst, int N,
    float* As /*16x68*/, float* Bs /*16x132*/)
{
  const int tid = threadIdx.x;
  const int tn = tid & 31, tm = tid >> 5;
  const int lr = tid >> 2, lc = (tid & 3) * 4;
  float acc[4][4];
#pragma unroll
  for (int i = 0; i < 4; ++i)
#pragma unroll
    for (int j = 0; j < 4; ++j) acc[i][j] = 0.f;

  const float* Wrow = W + (size_t)lr * ld + koff + lc;   // lr 0..127
  const float* Arow = A + (size_t)lr * ld + koff + lc;   // tid<256 (lr 0..63)

  for (int k0 = 0; k0 < KS; k0 += 16) {
    float4 b4 = *(const float4*)(Wrow + k0);
    if (tid < 256) {
      float a0 = dload(Arow + k0 + 0);
      float a1 = dload(Arow + k0 + 1);
      float a2 = dload(Arow + k0 + 2);
      float a3 = dload(Arow + k0 + 3);
      As[(lc + 0) * 68 + lr] = a0; As[(lc + 1) * 68 + lr] = a1;
      As[(lc + 2) * 68 + lr] = a2; As[(lc + 3) * 68 + lr] = a3;
    }
    Bs[(lc + 0) * 132 + lr] = b4.x; Bs[(lc + 1) * 132 + lr] = b4.y;
    Bs[(lc + 2) * 132 + lr] = b4.z; Bs[(lc + 3) * 132 + lr] = b4.w;
    __syncthreads();
#pragma unroll
    for (int k = 0; k < 16; ++k) {
      float av[4], bv[4];
      *(float4*)av = *(const float4*)(As + k * 68 + tm * 4);
      *(float4*)bv = *(const float4*)(Bs + k * 132 + tn * 4);
#pragma unroll
      for (int i = 0; i < 4; ++i)
#pragma unroll
        for (int j = 0; j < 4; ++j)
          acc[i][j] = fmaf(av[i], bv[j], acc[i][j]);
    }
    __syncthreads();
  }
#pragma unroll
  for (int i = 0; i < 4; ++i)
#pragma unroll
    for (int j = 0; j < 4; ++j)
      dstore(Pdst + (size_t)(tm * 4 + i) * N + tn * 4 + j, acc[i][j]);
}

__device__ __forceinline__ float sigm(float x) { return 1.f / (1.f + expf(-x)); }

__device__ __forceinline__ void ins3(float v, int i,
    float& v0, int& i0, float& v1, int& i1, float& v2, int& i2)
{
  if (v > v0 || (v == v0 && i < i0)) {
    v2 = v1; i2 = i1; v1 = v0; i1 = i0; v0 = v; i0 = i;
  } else if (v > v1 || (v == v1 && i < i1)) {
    v2 = v1; i2 = i1; v1 = v; i1 = i;
  } else if (v > v2 || (v == v2 && i < i2)) {
    v2 = v; i2 = i;
  }
}

// ---------------------------------------------------------------------------
// Persistent kernel: 256 blocks x 512 threads, all 24 steps, 9 barriers/step.
// ---------------------------------------------------------------------------
__global__ __launch_bounds__(512, 2) void decoder(Params p)
{
  __shared__ float smem[3200];
  float* As = smem;            // 16*68
  float* Bs = smem + 1088;     // 16*132

  const int tid = threadIdx.x;
  const int bid = blockIdx.x;
  const int gtid = bid * 512 + tid;

  // generation baseline (persists across launches; monotonic)
  unsigned tgt = __hip_atomic_load(&g_gen, __ATOMIC_RELAXED,
                                   __HIP_MEMORY_SCOPE_AGENT);

  for (int t = 0; t < S_; ++t) {
    const float* xin   = t ? p.xbuf : p.x0;
    const float* hprev = t ? p.hbuf : p.h0;
    const float* cprev = t ? p.cbuf : p.c0;

    // ---- 1: gates = [x|h] @ [W_ih|W_hh]^T -> P[8][64][4096], 256 tasks
    {
      int nb = bid & 31, sp = bid >> 5;
      int ks = sp * 512;
      const float* A; const float* W; int ld, koff;
      if (ks < 3072) { A = xin;   W = p.W_ih; ld = 3072; koff = ks; }
      else           { A = hprev; W = p.W_hh; ld = 1024; koff = ks - 3072; }
      gemm_tile(A, W + (size_t)nb * 128 * ld, ld, koff, 512,
                p.P + (size_t)sp * 64 * 4096 + nb * 128, 4096, As, Bs);
    }
    gbar(++tgt);

    // ---- 2: LSTM reduce + pointwise -> hbuf (agent), cbuf (block-local)
    if (gtid < 65536) {
      int b = gtid >> 10, j = gtid & 1023;
      float gv[4];
#pragma unroll
      for (int c = 0; c < 4; ++c) {
        int n = j + 1024 * c;
        float s = p.b_ih[n] + p.b_hh[n];
#pragma unroll
        for (int sp = 0; sp < 8; ++sp)
          s += dload(p.P + ((size_t)sp * 64 + b) * 4096 + n);
        gv[c] = s;
      }
      float c = sigm(gv[1]) * cprev[gtid] + sigm(gv[0]) * tanhf(gv[2]);
      p.cbuf[gtid] = c;                              // same block next step
      dstore(p.hbuf + gtid, sigm(gv[3]) * tanhf(c)); // read by everyone
    }
    gbar(++tgt);

    // ---- 3: qkv = h @ Wqkv^T -> P[8][64][3072], 192 tasks
    if (bid < 192) {
      int nb = bid % 24, sp = bid / 24;
      gemm_tile(p.hbuf, p.Wqkv + (size_t)nb * 128 * 1024, 1024, sp * 128, 128,
                p.P + (size_t)sp * 64 * 3072 + nb * 128, 3072, As, Bs);
    }
    gbar(++tgt);

    // ---- 4: attention (fused qkv reduce). 128 blocks x 4 quarters.
    if (bid < 128) {
      const float scale = 0.08838834764831845f;  // 1/sqrt(128)
      int q4 = tid >> 7, d = tid & 127;
      int task = bid * 4 + q4;                   // 0..511
      int b = task >> 3, h = task & 7;
      const float* Pb = p.P + (size_t)b * 3072 + h * 128 + d;
      float qv = p.bqkv[h * 128 + d];
      float kv = p.bqkv[1024 + h * 128 + d];
      float vv = p.bqkv[2048 + h * 128 + d];
#pragma unroll
      for (int sp = 0; sp < 8; ++sp) {
        const float* pp = Pb + (size_t)sp * 64 * 3072;
        qv += dload(pp); kv += dload(pp + 1024); vv += dload(pp + 2048);
      }
      // KV cache: written & read only by THIS block -> plain cached
      float* Kb = p.Kc + (size_t)(b * NH_ + h) * S_ * HD_;
      float* Vb = p.Vc + (size_t)(b * NH_ + h) * S_ * HD_;
      Kb[t * 128 + d] = kv;
      Vb[t * 128 + d] = vv;
      float* qs = smem + q4 * 128;         // 4*128
      float* sc = smem + 512 + q4 * 24;    // 4*24
      qs[d] = qv;
      __syncthreads();
      int wave = d >> 6, lane = d & 63;
      for (int s = wave; s <= t; s += 2) {
        float pr = qs[lane] * Kb[s * 128 + lane] + qs[lane + 64] * Kb[s * 128 + lane + 64];
#pragma unroll
        for (int off = 32; off > 0; off >>= 1) pr += __shfl_down(pr, off, 64);
        if (lane == 0) sc[s] = pr * scale;
      }
      __syncthreads();
      float m = -3.4e38f;
      for (int s = 0; s <= t; ++s) m = fmaxf(m, sc[s]);
      float den = 0.f;
      for (int s = 0; s <= t; ++s) den += expf(sc[s] - m);
      float acc = 0.f;
      for (int s = 0; s <= t; ++s) acc += expf(sc[s] - m) * Vb[s * 128 + d];
      dstore(p.ctx + (size_t)b * 1024 + h * 128 + d, acc / den);
    }
    gbar(++tgt);

    // ---- 5: attn_out = ctx @ Wout^T -> P[16][64][1024], 128 tasks
    if (bid < 128) {
      int nb = bid & 7, sp = bid >> 3;
      gemm_tile(p.ctx, p.Wout + (size_t)nb * 128 * 1024, 1024, sp * 64, 64,
                p.P + (size_t)sp * 64 * 1024 + nb * 128, 1024, As, Bs);
    }
    gbar(++tgt);

    // ---- 6: hq = 0.5*(h + attn_out-reduce)
    if (gtid < 65536) {
      int b = gtid >> 10, j = gtid & 1023;
      float s = p.bout[j];
#pragma unroll
      for (int sp = 0; sp < 16; ++sp)
        s += dload(p.P + ((size_t)sp * 64 + b) * 1024 + j);
      dstore(p.hq + gtid, 0.5f * (dload(p.hbuf + gtid) + s));
    }
    gbar(++tgt);

    // ---- 7: qt = hq @ Wqt^T -> P[16][64][1024], 128 tasks
    if (bid < 128) {
      int nb = bid & 7, sp = bid >> 3;
      gemm_tile(p.hq, p.Wqt + (size_t)nb * 128 * 1024, 1024, sp * 64, 64,
                p.P + (size_t)sp * 64 * 1024 + nb * 128, 1024, As, Bs);
    }
    gbar(++tgt);

    // ---- 8: logits (fused qt reduce). One b per 4 blocks, 128 n each.
    float* lo = p.logits + (size_t)t * B_ * N_;
    {
      int b = bid >> 2, ng = bid & 3;       // 128 n per block
      for (int i = tid; i < 1024; i += 512) {
        float s = p.bqt[i];
#pragma unroll
        for (int sp = 0; sp < 16; ++sp)
          s += dload(p.P + ((size_t)sp * 64 + b) * 1024 + i);
        smem[i] = s;
      }
      __syncthreads();
      int wave = tid >> 6, lane = tid & 63;
      for (int j = 0; j < 16; ++j) {
        int n = ng * 128 + wave * 16 + j;
        const float* e = p.enc + ((size_t)b * N_ + n) * 1024;
        float pr = 0.f;
#pragma unroll
        for (int i = 0; i < 16; ++i) pr = fmaf(smem[lane + 64 * i], e[lane + 64 * i], pr);
#pragma unroll
        for (int off = 32; off > 0; off >>= 1) pr += __shfl_down(pr, off, 64);
        if (lane == 0) dstore(lo + (size_t)b * N_ + n, pr);
      }
    }
    gbar(++tgt);

    // ---- 9: top3 + gather next x. 64 blocks.
    if (bid < 64) {
      int b = bid;
      float* sv = smem;                       // 192 floats
      int*   si = (int*)(smem + 192);         // 192 ints
      int*   topi = (int*)(smem + 384);
      const float* lrow = lo + (size_t)b * N_;
      if (tid < 64) {
        float v0 = -3.4e38f, v1 = -3.4e38f, v2 = -3.4e38f;
        int i0 = 0x7fffffff, i1 = 0x7fffffff, i2 = 0x7fffffff;
        for (int n = tid; n < N_; n += 64) ins3(dload(lrow + n), n, v0, i0, v1, i1, v2, i2);
        sv[tid * 3 + 0] = v0; si[tid * 3 + 0] = i0;
        sv[tid * 3 + 1] = v1; si[tid * 3 + 1] = i1;
        sv[tid * 3 + 2] = v2; si[tid * 3 + 2] = i2;
      }
      __syncthreads();
      if (tid == 0) {
        float w0 = -3.4e38f, w1 = -3.4e38f, w2 = -3.4e38f;
        int j0 = 0x7fffffff, j1 = 0x7fffffff, j2 = 0x7fffffff;
        for (int k = 0; k < 192; ++k) ins3(sv[k], si[k], w0, j0, w1, j1, w2, j2);
        int a = j0, bb = j1, c = j2, tw;
        if (a > bb) { tw = a; a = bb; bb = tw; }
        if (bb > c) { tw = bb; bb = c; c = tw; }
        if (a > bb) { tw = a; a = bb; bb = tw; }
        topi[0] = a; topi[1] = bb; topi[2] = c;
        float* io = p.idx + (size_t)t * B_ * 3 + b * 3;
        io[0] = (float)a; io[1] = (float)bb; io[2] = (float)c;
      }
      __syncthreads();
      for (int r = 0; r < 3; ++r) {
        const float* e = p.enc + ((size_t)b * N_ + topi[r]) * 1024;
        for (int i = tid; i < 1024; i += 512)
          dstore(p.xbuf + (size_t)b * 3072 + r * 1024 + i, e[i]);
      }
    }
    gbar(++tgt);
  }
}

// ---------------------------------------------------------------------------
extern "C" void kernel_launch(void* const* d_in, const int* in_sizes, int n_in,
                              void* d_out, int out_size, void* d_ws, size_t ws_size,
                              hipStream_t stream)
{
  (void)in_sizes; (void)n_in; (void)out_size; (void)ws_size;
  Params p;
  p.enc   = (const float*)d_in[0];
  p.h0    = (const float*)d_in[1];
  p.c0    = (const float*)d_in[2];
  p.x0    = (const float*)d_in[4];
  p.W_ih  = (const float*)d_in[6];
  p.b_ih  = (const float*)d_in[7];
  p.W_hh  = (const float*)d_in[8];
  p.b_hh  = (const float*)d_in[9];
  p.Wqkv  = (const float*)d_in[10];
  p.bqkv  = (const float*)d_in[11];
  p.Wout  = (const float*)d_in[12];
  p.bout  = (const float*)d_in[13];
  p.Wqt   = (const float*)d_in[14];
  p.bqt   = (const float*)d_in[15];

  float* ws = (float*)d_ws;
  p.P    = ws;                          // 8*64*4096 floats (phase-shared)
  p.hbuf = p.P + 8 * 64 * 4096;
  p.cbuf = p.hbuf + 64 * 1024;
  p.hq   = p.cbuf + 64 * 1024;
  p.ctx  = p.hq + 64 * 1024;
  p.xbuf = p.ctx + 64 * 1024;           // 64*3072
  p.Kc   = p.xbuf + 64 * 3072;          // 64*8*24*128
  p.Vc   = p.Kc + 64 * NH_ * S_ * HD_;

  p.logits = (float*)d_out;                       // [S,B,N]
  p.idx    = p.logits + (size_t)S_ * B_ * N_;     // [S,B,3] as float

  void* args[] = { &p };
  hipLaunchCooperativeKernel((void*)decoder, dim3(NBLK), dim3(512), args, 0, stream);
}

// Round 6
// 4770.398 us; speedup vs baseline: 4.2031x; 1.8139x over previous
//
#include <hip/hip_runtime.h>
#include <math.h>

#define B_  64
#define N_  512
#define H_  1024
#define NH_ 8
#define HD_ 128
#define S_  24

// ---------------------------------------------------------------------------
// Precompute: W2[n][0..1023] = 0.5*Wqt[n][k];  W2[n][1024+k] = 0.5*(Wqt·Wout)[n][k]
// 256 blocks: 16x16 grid of 64x64 tiles. 256 threads, 4x4 acc.
// ---------------------------------------------------------------------------
__global__ __launch_bounds__(256) void wc_pre(
    const float* __restrict__ Wqt, const float* __restrict__ Wout,
    float* __restrict__ W2)
{
  __shared__ float As[16][68];   // [m][n] of Wqt tile (transposed stage)
  __shared__ float Bs[16][68];   // [m][k] of Wout tile
  const int tid = threadIdx.x;
  const int k0 = (blockIdx.x & 15) * 64;
  const int n0 = (blockIdx.x >> 4) * 64;
  const int tn = tid & 15, tm = tid >> 4;

  // copy half: W2[n][k] = 0.5*Wqt[n][k]
#pragma unroll
  for (int i = 0; i < 4; ++i) {
    int n = n0 + tm * 4 + i;
    float4 w = *(const float4*)(Wqt + (size_t)n * 1024 + k0 + tn * 4);
    *(float4*)(W2 + (size_t)n * 2048 + k0 + tn * 4) =
        make_float4(0.5f * w.x, 0.5f * w.y, 0.5f * w.z, 0.5f * w.w);
  }

  float acc[4][4];
#pragma unroll
  for (int i = 0; i < 4; ++i)
#pragma unroll
    for (int j = 0; j < 4; ++j) acc[i][j] = 0.f;

  for (int m0 = 0; m0 < 1024; m0 += 16) {
    {
      int nn = tid >> 2, mm = (tid & 3) * 4;
      float4 a = *(const float4*)(Wqt + (size_t)(n0 + nn) * 1024 + m0 + mm);
      As[mm + 0][nn] = a.x; As[mm + 1][nn] = a.y;
      As[mm + 2][nn] = a.z; As[mm + 3][nn] = a.w;
      int mr = tid >> 4, kc = (tid & 15) * 4;
      float4 b = *(const float4*)(Wout + (size_t)(m0 + mr) * 1024 + k0 + kc);
      *(float4*)(&Bs[mr][kc]) = b;
    }
    __syncthreads();
#pragma unroll
    for (int m = 0; m < 16; ++m) {
      float av[4], bv[4];
      *(float4*)av = *(const float4*)(&As[m][tm * 4]);
      *(float4*)bv = *(const float4*)(&Bs[m][tn * 4]);
#pragma unroll
      for (int i = 0; i < 4; ++i)
#pragma unroll
        for (int j = 0; j < 4; ++j)
          acc[i][j] = fmaf(av[i], bv[j], acc[i][j]);
    }
    __syncthreads();
  }
#pragma unroll
  for (int i = 0; i < 4; ++i) {
    int n = n0 + tm * 4 + i;
    *(float4*)(W2 + (size_t)n * 2048 + 1024 + k0 + tn * 4) =
        make_float4(0.5f * acc[i][0], 0.5f * acc[i][1],
                    0.5f * acc[i][2], 0.5f * acc[i][3]);
  }
}

// bc[n] = 0.5*dot(Wqt[n,:], bout) + bqt[n].  256 blocks x 256 thr, wave per n.
__global__ __launch_bounds__(256) void bc_pre(
    const float* __restrict__ Wqt, const float* __restrict__ bout,
    const float* __restrict__ bqt, float* __restrict__ bc)
{
  int w = threadIdx.x >> 6, lane = threadIdx.x & 63;
  int n = blockIdx.x * 4 + w;
  const float* row = Wqt + (size_t)n * 1024;
  float s = 0.f;
#pragma unroll
  for (int c = 0; c < 4; ++c) {
    float4 a = *(const float4*)(row + lane * 16 + c * 4);
    float4 b = *(const float4*)(bout + lane * 16 + c * 4);
    s = fmaf(a.x, b.x, fmaf(a.y, b.y, fmaf(a.z, b.z, fmaf(a.w, b.w, s))));
  }
#pragma unroll
  for (int off = 32; off > 0; off >>= 1) s += __shfl_down(s, off, 64);
  if (lane == 0) bc[n] = 0.5f * s + bqt[n];
}

// ---------------------------------------------------------------------------
// Split-K GEMM: P[sp][64][N] = A[64,K-slice] @ W[N,K-slice]^T
// Two K-segments with independent (A, ldA, W, ldW); koff = ks or ks-K0.
// Tile 64m x 128n, 512 threads, KS per split. Optional seg0 A-gather:
// A row b = enc[b*512 + idxi[b*3 + (koff>>10)]] (x = top3-gathered enc rows).
// ---------------------------------------------------------------------------
__global__ __launch_bounds__(512, 2) void gemm5(
    const float* __restrict__ A0, int ldA0, const float* __restrict__ W0, int ldW0,
    int K0,
    const float* __restrict__ A1, int ldA1, const float* __restrict__ W1, int ldW1,
    const float* __restrict__ enc, const int* __restrict__ idxi, int gather,
    float* __restrict__ P, int N, int KS)
{
  __shared__ float As[16 * 68];
  __shared__ float Bs[16 * 132];
  const int tid = threadIdx.x;
  const int nb = blockIdx.x, sp = blockIdx.y;
  const int ks = sp * KS;

  const float* A; const float* W; int ldA, ldW, koff; int seg0;
  if (ks < K0) { A = A0; W = W0; ldA = ldA0; ldW = ldW0; koff = ks; seg0 = 1; }
  else { A = A1; W = W1; ldA = ldA1; ldW = ldW1; koff = ks - K0; seg0 = 0; }

  const int tn = tid & 31, tm = tid >> 5;
  const int lr = tid >> 2, lc = (tid & 3) * 4;

  float acc[4][4];
#pragma unroll
  for (int i = 0; i < 4; ++i)
#pragma unroll
    for (int j = 0; j < 4; ++j) acc[i][j] = 0.f;

  const float* Wrow = W + (size_t)(nb * 128 + lr) * ldW + koff + lc;
  const float* Arow = nullptr;
  if (tid < 256) {
    if (seg0 && gather) {
      int ei = idxi[lr * 3 + (koff >> 10)];
      Arow = enc + ((size_t)lr * 512 + ei) * 1024 + (koff & 1023) + lc;
    } else {
      Arow = A + (size_t)lr * ldA + koff + lc;
    }
  }

  for (int k0 = 0; k0 < KS; k0 += 16) {
    float4 b4 = *(const float4*)(Wrow + k0);
    if (tid < 256) {
      float4 a4 = *(const float4*)(Arow + k0);
      As[(lc + 0) * 68 + lr] = a4.x; As[(lc + 1) * 68 + lr] = a4.y;
      As[(lc + 2) * 68 + lr] = a4.z; As[(lc + 3) * 68 + lr] = a4.w;
    }
    Bs[(lc + 0) * 132 + lr] = b4.x; Bs[(lc + 1) * 132 + lr] = b4.y;
    Bs[(lc + 2) * 132 + lr] = b4.z; Bs[(lc + 3) * 132 + lr] = b4.w;
    __syncthreads();
#pragma unroll
    for (int k = 0; k < 16; ++k) {
      float av[4], bv[4];
      *(float4*)av = *(const float4*)(As + k * 68 + tm * 4);
      *(float4*)bv = *(const float4*)(Bs + k * 132 + tn * 4);
#pragma unroll
      for (int i = 0; i < 4; ++i)
#pragma unroll
        for (int j = 0; j < 4; ++j)
          acc[i][j] = fmaf(av[i], bv[j], acc[i][j]);
    }
    __syncthreads();
  }
  float* Pb = P + (size_t)sp * 64 * N + nb * 128;
#pragma unroll
  for (int i = 0; i < 4; ++i)
    *(float4*)(Pb + (size_t)(tm * 4 + i) * N + tn * 4) =
        make_float4(acc[i][0], acc[i][1], acc[i][2], acc[i][3]);
}

// ---------------------------------------------------------------------------
// LSTM: reduce 8 gate partials + biases, pointwise -> h', c'.  float4 wide.
// 64 blocks x 256 threads, 4 elements/thread.
// ---------------------------------------------------------------------------
__device__ __forceinline__ float sigm(float x) { return 1.f / (1.f + expf(-x)); }

__global__ __launch_bounds__(256) void lstm_red(
    const float* __restrict__ P, const float* __restrict__ b_ih,
    const float* __restrict__ b_hh, const float* __restrict__ c_in,
    float* __restrict__ h_out, float* __restrict__ c_out)
{
  int idx = blockIdx.x * 256 + threadIdx.x;   // 0..16383
  int b = idx >> 8, j4 = (idx & 255) * 4;
  float g[4][4];
#pragma unroll
  for (int c = 0; c < 4; ++c) {
    int n = c * 1024 + j4;
    float4 s = *(const float4*)(b_ih + n);
    float4 s2 = *(const float4*)(b_hh + n);
    s.x += s2.x; s.y += s2.y; s.z += s2.z; s.w += s2.w;
#pragma unroll
    for (int sp = 0; sp < 8; ++sp) {
      float4 v = *(const float4*)(P + ((size_t)sp * 64 + b) * 4096 + n);
      s.x += v.x; s.y += v.y; s.z += v.z; s.w += v.w;
    }
    g[c][0] = s.x; g[c][1] = s.y; g[c][2] = s.z; g[c][3] = s.w;
  }
  float4 cp = *(const float4*)(c_in + b * 1024 + j4);
  float cv[4] = {cp.x, cp.y, cp.z, cp.w};
  float4 ho, co;
  float* hp = &ho.x; float* cpn = &co.x;
#pragma unroll
  for (int e = 0; e < 4; ++e) {
    float c = sigm(g[1][e]) * cv[e] + sigm(g[0][e]) * tanhf(g[2][e]);
    cpn[e] = c;
    hp[e] = sigm(g[3][e]) * tanhf(c);
  }
  *(float4*)(c_out + b * 1024 + j4) = co;
  *(float4*)(h_out + b * 1024 + j4) = ho;
}

// ---------------------------------------------------------------------------
// Attention with fused qkv-partial reduce. 512 blocks (b,h) x 128 threads.
// ---------------------------------------------------------------------------
__global__ __launch_bounds__(128) void attn_fused(
    const float* __restrict__ P, const float* __restrict__ bqkv,
    float* __restrict__ Kc, float* __restrict__ Vc,
    float* __restrict__ ctx, int t)
{
  const float scale = 0.08838834764831845f;  // 1/sqrt(128)
  int bh = blockIdx.x;
  int b = bh >> 3, h = bh & 7;
  int d = threadIdx.x;
  __shared__ float qs[128];
  __shared__ float sc[S_];

  const float* Pb = P + (size_t)b * 3072 + h * 128 + d;
  float qv = bqkv[h * 128 + d];
  float kv = bqkv[1024 + h * 128 + d];
  float vv = bqkv[2048 + h * 128 + d];
#pragma unroll
  for (int sp = 0; sp < 8; ++sp) {
    const float* pp = Pb + (size_t)sp * 64 * 3072;
    qv += pp[0]; kv += pp[1024]; vv += pp[2048];
  }
  float* Kb = Kc + (size_t)(b * NH_ + h) * S_ * HD_;
  float* Vb = Vc + (size_t)(b * NH_ + h) * S_ * HD_;
  Kb[t * 128 + d] = kv;
  Vb[t * 128 + d] = vv;
  qs[d] = qv;
  __syncthreads();

  int wave = d >> 6, lane = d & 63;
  for (int s = wave; s <= t; s += 2) {
    float pr = qs[lane] * Kb[s * 128 + lane] + qs[lane + 64] * Kb[s * 128 + lane + 64];
#pragma unroll
    for (int off = 32; off > 0; off >>= 1) pr += __shfl_down(pr, off, 64);
    if (lane == 0) sc[s] = pr * scale;
  }
  __syncthreads();

  float m = -3.4e38f;
  for (int s = 0; s <= t; ++s) m = fmaxf(m, sc[s]);
  float den = 0.f;
  for (int s = 0; s <= t; ++s) den += expf(sc[s] - m);
  float acc = 0.f;
  for (int s = 0; s <= t; ++s) acc += expf(sc[s] - m) * Vb[s * 128 + d];
  ctx[(size_t)b * 1024 + h * 128 + d] = acc / den;
}

// ---------------------------------------------------------------------------
// logits with fused qt-partial reduce. 256 blocks x 512 thr; b = bid>>2,
// 128 n per block.
// ---------------------------------------------------------------------------
__global__ __launch_bounds__(512) void logits_fused(
    const float* __restrict__ P, const float* __restrict__ bc,
    const float* __restrict__ enc, float* __restrict__ out)
{
  __shared__ float qs[1024];
  int tid = threadIdx.x;
  int b = blockIdx.x >> 2, ng = blockIdx.x & 3;
  for (int i = tid; i < 1024; i += 512) {
    float s = bc[i];
#pragma unroll
    for (int sp = 0; sp < 16; ++sp) s += P[((size_t)sp * 64 + b) * 1024 + i];
    qs[i] = s;
  }
  __syncthreads();
  int wave = tid >> 6, lane = tid & 63;
  for (int j = 0; j < 16; ++j) {
    int n = ng * 128 + wave * 16 + j;
    const float* e = enc + ((size_t)b * N_ + n) * 1024;
    float pr = 0.f;
#pragma unroll
    for (int i = 0; i < 16; ++i) pr = fmaf(qs[lane + 64 * i], e[lane + 64 * i], pr);
#pragma unroll
    for (int off = 32; off > 0; off >>= 1) pr += __shfl_down(pr, off, 64);
    if (lane == 0) out[(size_t)b * N_ + n] = pr;
  }
}

// ---------------------------------------------------------------------------
// Top-3 (desc value, tie -> lower idx), idx sorted ascending. Writes float idx
// to d_out and int idx to ws (consumed by next step's gates gather).
// ---------------------------------------------------------------------------
__device__ __forceinline__ void ins3(float v, int i,
    float& v0, int& i0, float& v1, int& i1, float& v2, int& i2)
{
  if (v > v0 || (v == v0 && i < i0)) {
    v2 = v1; i2 = i1; v1 = v0; i1 = i0; v0 = v; i0 = i;
  } else if (v > v1 || (v == v1 && i < i1)) {
    v2 = v1; i2 = i1; v1 = v; i1 = i;
  } else if (v > v2 || (v == v2 && i < i2)) {
    v2 = v; i2 = i;
  }
}

__global__ __launch_bounds__(64) void top3_k(
    const float* __restrict__ logits, float* __restrict__ idx_out,
    int* __restrict__ idxi)
{
  int b = blockIdx.x;
  int tid = threadIdx.x;
  float v0 = -3.4e38f, v1 = -3.4e38f, v2 = -3.4e38f;
  int i0 = 0x7fffffff, i1 = 0x7fffffff, i2 = 0x7fffffff;
  for (int n = tid; n < N_; n += 64) {
    float v = logits[(size_t)b * N_ + n];
    ins3(v, n, v0, i0, v1, i1, v2, i2);
  }
  __shared__ float sv[192];
  __shared__ int   si[192];
  sv[tid * 3 + 0] = v0; si[tid * 3 + 0] = i0;
  sv[tid * 3 + 1] = v1; si[tid * 3 + 1] = i1;
  sv[tid * 3 + 2] = v2; si[tid * 3 + 2] = i2;
  __syncthreads();
  if (tid == 0) {
    float w0 = -3.4e38f, w1 = -3.4e38f, w2 = -3.4e38f;
    int j0 = 0x7fffffff, j1 = 0x7fffffff, j2 = 0x7fffffff;
    for (int k = 0; k < 192; ++k) ins3(sv[k], si[k], w0, j0, w1, j1, w2, j2);
    int a = j0, bb = j1, c = j2, tw;
    if (a > bb) { tw = a; a = bb; bb = tw; }
    if (bb > c) { tw = bb; bb = c; c = tw; }
    if (a > bb) { tw = a; a = bb; bb = tw; }
    idxi[b * 3 + 0] = a; idxi[b * 3 + 1] = bb; idxi[b * 3 + 2] = c;
    idx_out[b * 3 + 0] = (float)a;
    idx_out[b * 3 + 1] = (float)bb;
    idx_out[b * 3 + 2] = (float)c;
  }
}

// ---------------------------------------------------------------------------
extern "C" void kernel_launch(void* const* d_in, const int* in_sizes, int n_in,
                              void* d_out, int out_size, void* d_ws, size_t ws_size,
                              hipStream_t stream)
{
  (void)in_sizes; (void)n_in; (void)out_size; (void)ws_size;
  const float* enc   = (const float*)d_in[0];
  const float* h0    = (const float*)d_in[1];
  const float* c0    = (const float*)d_in[2];
  const float* x0    = (const float*)d_in[4];
  const float* W_ih  = (const float*)d_in[6];
  const float* b_ih  = (const float*)d_in[7];
  const float* W_hh  = (const float*)d_in[8];
  const float* b_hh  = (const float*)d_in[9];
  const float* Wqkv  = (const float*)d_in[10];
  const float* bqkv  = (const float*)d_in[11];
  const float* Wout  = (const float*)d_in[12];
  const float* bout  = (const float*)d_in[13];
  const float* Wqt   = (const float*)d_in[14];
  const float* bqt   = (const float*)d_in[15];

  float* ws   = (float*)d_ws;
  float* P    = ws;                          // 8*64*4096 = 2.097M floats max
  float* W2   = P + 8 * 64 * 4096;           // 1024*2048 = 2.097M
  float* bc   = W2 + 1024 * 2048;            // 1024
  float* hbuf = bc + 1024;                   // 64*1024
  float* cbuf = hbuf + 64 * 1024;
  float* ctx  = cbuf + 64 * 1024;
  float* Kc   = ctx + 64 * 1024;             // 64*8*24*128
  float* Vc   = Kc + 64 * NH_ * S_ * HD_;
  int*   idxi = (int*)(Vc + 64 * NH_ * S_ * HD_);   // 192 ints

  float* logits_out = (float*)d_out;                     // [S,B,N]
  float* idx_out    = logits_out + (size_t)S_ * B_ * N_; // [S,B,3] as float

  // once per launch: combined qt weights/bias (step-invariant)
  wc_pre<<<dim3(256), dim3(256), 0, stream>>>(Wqt, Wout, W2);
  bc_pre<<<dim3(256), dim3(256), 0, stream>>>(Wqt, bout, bqt, bc);

  for (int t = 0; t < S_; ++t) {
    const float* xin   = (t == 0) ? x0 : nullptr;   // t>0: gather from enc
    const float* hprev = (t == 0) ? h0 : hbuf;
    const float* cprev = (t == 0) ? c0 : cbuf;

    // gates = [x|h] @ [W_ih|W_hh]^T -> P[8][64][4096]
    gemm5<<<dim3(32, 8), dim3(512), 0, stream>>>(
        xin, 3072, W_ih, 3072, 3072,
        hprev, 1024, W_hh, 1024,
        enc, idxi, t > 0, P, 4096, 512);
    lstm_red<<<dim3(64), dim3(256), 0, stream>>>(P, b_ih, b_hh, cprev, hbuf, cbuf);

    // qkv = h @ Wqkv^T -> P[8][64][3072]
    gemm5<<<dim3(24, 8), dim3(512), 0, stream>>>(
        hbuf, 1024, Wqkv, 1024, 1024,
        hbuf, 1024, Wqkv, 1024,
        enc, idxi, 0, P, 3072, 128);
    attn_fused<<<dim3(512), dim3(128), 0, stream>>>(P, bqkv, Kc, Vc, ctx, t);

    // query = [h|ctx] @ W2^T (+bc at reduce) -> P[16][64][1024]
    gemm5<<<dim3(8, 16), dim3(512), 0, stream>>>(
        hbuf, 1024, W2, 2048, 1024,
        ctx, 1024, W2 + 1024, 2048,
        enc, idxi, 0, P, 1024, 128);
    logits_fused<<<dim3(256), dim3(512), 0, stream>>>(
        P, bc, enc, logits_out + (size_t)t * B_ * N_);
    top3_k<<<dim3(64), dim3(64), 0, stream>>>(
        logits_out + (size_t)t * B_ * N_,
        idx_out + (size_t)t * B_ * 3, idxi);
  }
}

// Round 7
// 3597.123 us; speedup vs baseline: 5.5740x; 1.3262x over previous
//
#include <hip/hip_runtime.h>
#include <math.h>

#define B_  64
#define N_  512
#define H_  1024
#define NH_ 8
#define HD_ 128
#define S_  24

// ---------------------------------------------------------------------------
// Precompute: W2[n][0..1023] = 0.5*Wqt[n][k];  W2[n][1024+k] = 0.5*(Wqt·Wout)[n][k]
// 256 blocks: 16x16 grid of 64x64 tiles. 256 threads, 4x4 acc.
// ---------------------------------------------------------------------------
__global__ __launch_bounds__(256) void wc_pre(
    const float* __restrict__ Wqt, const float* __restrict__ Wout,
    float* __restrict__ W2)
{
  __shared__ float As[16][68];   // [m][n] of Wqt tile (transposed stage)
  __shared__ float Bs[16][68];   // [m][k] of Wout tile
  const int tid = threadIdx.x;
  const int k0 = (blockIdx.x & 15) * 64;
  const int n0 = (blockIdx.x >> 4) * 64;
  const int tn = tid & 15, tm = tid >> 4;

  // copy half: W2[n][k] = 0.5*Wqt[n][k]
#pragma unroll
  for (int i = 0; i < 4; ++i) {
    int n = n0 + tm * 4 + i;
    float4 w = *(const float4*)(Wqt + (size_t)n * 1024 + k0 + tn * 4);
    *(float4*)(W2 + (size_t)n * 2048 + k0 + tn * 4) =
        make_float4(0.5f * w.x, 0.5f * w.y, 0.5f * w.z, 0.5f * w.w);
  }

  float acc[4][4];
#pragma unroll
  for (int i = 0; i < 4; ++i)
#pragma unroll
    for (int j = 0; j < 4; ++j) acc[i][j] = 0.f;

  for (int m0 = 0; m0 < 1024; m0 += 16) {
    {
      int nn = tid >> 2, mm = (tid & 3) * 4;
      float4 a = *(const float4*)(Wqt + (size_t)(n0 + nn) * 1024 + m0 + mm);
      As[mm + 0][nn] = a.x; As[mm + 1][nn] = a.y;
      As[mm + 2][nn] = a.z; As[mm + 3][nn] = a.w;
      int mr = tid >> 4, kc = (tid & 15) * 4;
      float4 b = *(const float4*)(Wout + (size_t)(m0 + mr) * 1024 + k0 + kc);
      *(float4*)(&Bs[mr][kc]) = b;
    }
    __syncthreads();
#pragma unroll
    for (int m = 0; m < 16; ++m) {
      float av[4], bv[4];
      *(float4*)av = *(const float4*)(&As[m][tm * 4]);
      *(float4*)bv = *(const float4*)(&Bs[m][tn * 4]);
#pragma unroll
      for (int i = 0; i < 4; ++i)
#pragma unroll
        for (int j = 0; j < 4; ++j)
          acc[i][j] = fmaf(av[i], bv[j], acc[i][j]);
    }
    __syncthreads();
  }
#pragma unroll
  for (int i = 0; i < 4; ++i) {
    int n = n0 + tm * 4 + i;
    *(float4*)(W2 + (size_t)n * 2048 + 1024 + k0 + tn * 4) =
        make_float4(0.5f * acc[i][0], 0.5f * acc[i][1],
                    0.5f * acc[i][2], 0.5f * acc[i][3]);
  }
}

// bc[n] = 0.5*dot(Wqt[n,:], bout) + bqt[n].  256 blocks x 256 thr, wave per n.
__global__ __launch_bounds__(256) void bc_pre(
    const float* __restrict__ Wqt, const float* __restrict__ bout,
    const float* __restrict__ bqt, float* __restrict__ bc)
{
  int w = threadIdx.x >> 6, lane = threadIdx.x & 63;
  int n = blockIdx.x * 4 + w;
  const float* row = Wqt + (size_t)n * 1024;
  float s = 0.f;
#pragma unroll
  for (int c = 0; c < 4; ++c) {
    float4 a = *(const float4*)(row + lane * 16 + c * 4);
    float4 b = *(const float4*)(bout + lane * 16 + c * 4);
    s = fmaf(a.x, b.x, fmaf(a.y, b.y, fmaf(a.z, b.z, fmaf(a.w, b.w, s))));
  }
#pragma unroll
  for (int off = 32; off > 0; off >>= 1) s += __shfl_down(s, off, 64);
  if (lane == 0) bc[n] = 0.5f * s + bqt[n];
}

// ---------------------------------------------------------------------------
// Split-K GEMM: P[sp][64][N] = A[64,K-slice] @ W[N,K-slice]^T
// Two K-segments with independent (A, ldA, W, ldW); koff = ks or ks-K0.
// Tile 64m x 128n, 512 threads, KS per split. Optional seg0 A-gather:
// A row b = enc[b*512 + idxi[b*3 + (koff>>10)]] (x = top3-gathered enc rows).
// ---------------------------------------------------------------------------
__global__ __launch_bounds__(512, 2) void gemm5(
    const float* __restrict__ A0, int ldA0, const float* __restrict__ W0, int ldW0,
    int K0,
    const float* __restrict__ A1, int ldA1, const float* __restrict__ W1, int ldW1,
    const float* __restrict__ enc, const int* __restrict__ idxi, int gather,
    float* __restrict__ P, int N, int KS)
{
  __shared__ float As[16 * 68];
  __shared__ float Bs[16 * 132];
  const int tid = threadIdx.x;
  const int nb = blockIdx.x, sp = blockIdx.y;
  const int ks = sp * KS;

  const float* A; const float* W; int ldA, ldW, koff; int seg0;
  if (ks < K0) { A = A0; W = W0; ldA = ldA0; ldW = ldW0; koff = ks; seg0 = 1; }
  else { A = A1; W = W1; ldA = ldA1; ldW = ldW1; koff = ks - K0; seg0 = 0; }

  const int tn = tid & 31, tm = tid >> 5;
  const int lr = tid >> 2, lc = (tid & 3) * 4;

  float acc[4][4];
#pragma unroll
  for (int i = 0; i < 4; ++i)
#pragma unroll
    for (int j = 0; j < 4; ++j) acc[i][j] = 0.f;

  const float* Wrow = W + (size_t)(nb * 128 + lr) * ldW + koff + lc;
  const float* Arow = nullptr;
  if (tid < 256) {
    if (seg0 && gather) {
      int ei = idxi[lr * 3 + (koff >> 10)];
      Arow = enc + ((size_t)lr * 512 + ei) * 1024 + (koff & 1023) + lc;
    } else {
      Arow = A + (size_t)lr * ldA + koff + lc;
    }
  }

  for (int k0 = 0; k0 < KS; k0 += 16) {
    float4 b4 = *(const float4*)(Wrow + k0);
    if (tid < 256) {
      float4 a4 = *(const float4*)(Arow + k0);
      As[(lc + 0) * 68 + lr] = a4.x; As[(lc + 1) * 68 + lr] = a4.y;
      As[(lc + 2) * 68 + lr] = a4.z; As[(lc + 3) * 68 + lr] = a4.w;
    }
    Bs[(lc + 0) * 132 + lr] = b4.x; Bs[(lc + 1) * 132 + lr] = b4.y;
    Bs[(lc + 2) * 132 + lr] = b4.z; Bs[(lc + 3) * 132 + lr] = b4.w;
    __syncthreads();
#pragma unroll
    for (int k = 0; k < 16; ++k) {
      float av[4], bv[4];
      *(float4*)av = *(const float4*)(As + k * 68 + tm * 4);
      *(float4*)bv = *(const float4*)(Bs + k * 132 + tn * 4);
#pragma unroll
      for (int i = 0; i < 4; ++i)
#pragma unroll
        for (int j = 0; j < 4; ++j)
          acc[i][j] = fmaf(av[i], bv[j], acc[i][j]);
    }
    __syncthreads();
  }
  float* Pb = P + (size_t)sp * 64 * N + nb * 128;
#pragma unroll
  for (int i = 0; i < 4; ++i)
    *(float4*)(Pb + (size_t)(tm * 4 + i) * N + tn * 4) =
        make_float4(acc[i][0], acc[i][1], acc[i][2], acc[i][3]);
}

// ---------------------------------------------------------------------------
// LSTM: reduce 8 gate partials + biases, pointwise -> h', c'.  float4 wide.
// ---------------------------------------------------------------------------
__device__ __forceinline__ float sigm(float x) { return 1.f / (1.f + expf(-x)); }

__global__ __launch_bounds__(256) void lstm_red(
    const float* __restrict__ P, const float* __restrict__ b_ih,
    const float* __restrict__ b_hh, const float* __restrict__ c_in,
    float* __restrict__ h_out, float* __restrict__ c_out)
{
  int idx = blockIdx.x * 256 + threadIdx.x;   // 0..16383
  int b = idx >> 8, j4 = (idx & 255) * 4;
  float g[4][4];
#pragma unroll
  for (int c = 0; c < 4; ++c) {
    int n = c * 1024 + j4;
    float4 s = *(const float4*)(b_ih + n);
    float4 s2 = *(const float4*)(b_hh + n);
    s.x += s2.x; s.y += s2.y; s.z += s2.z; s.w += s2.w;
#pragma unroll
    for (int sp = 0; sp < 8; ++sp) {
      float4 v = *(const float4*)(P + ((size_t)sp * 64 + b) * 4096 + n);
      s.x += v.x; s.y += v.y; s.z += v.z; s.w += v.w;
    }
    g[c][0] = s.x; g[c][1] = s.y; g[c][2] = s.z; g[c][3] = s.w;
  }
  float4 cp = *(const float4*)(c_in + b * 1024 + j4);
  float cv[4] = {cp.x, cp.y, cp.z, cp.w};
  float4 ho, co;
  float* hp = &ho.x; float* cpn = &co.x;
#pragma unroll
  for (int e = 0; e < 4; ++e) {
    float c = sigm(g[1][e]) * cv[e] + sigm(g[0][e]) * tanhf(g[2][e]);
    cpn[e] = c;
    hp[e] = sigm(g[3][e]) * tanhf(c);
  }
  *(float4*)(c_out + b * 1024 + j4) = co;
  *(float4*)(h_out + b * 1024 + j4) = ho;
}

// ---------------------------------------------------------------------------
// Attention with fused qkv-partial reduce. 512 blocks (b,h) x 128 threads.
// ---------------------------------------------------------------------------
__global__ __launch_bounds__(128) void attn_fused(
    const float* __restrict__ P, const float* __restrict__ bqkv,
    float* __restrict__ Kc, float* __restrict__ Vc,
    float* __restrict__ ctx, int t)
{
  const float scale = 0.08838834764831845f;  // 1/sqrt(128)
  int bh = blockIdx.x;
  int b = bh >> 3, h = bh & 7;
  int d = threadIdx.x;
  __shared__ float qs[128];
  __shared__ float sc[S_];

  const float* Pb = P + (size_t)b * 3072 + h * 128 + d;
  float qv = bqkv[h * 128 + d];
  float kv = bqkv[1024 + h * 128 + d];
  float vv = bqkv[2048 + h * 128 + d];
#pragma unroll
  for (int sp = 0; sp < 8; ++sp) {
    const float* pp = Pb + (size_t)sp * 64 * 3072;
    qv += pp[0]; kv += pp[1024]; vv += pp[2048];
  }
  float* Kb = Kc + (size_t)(b * NH_ + h) * S_ * HD_;
  float* Vb = Vc + (size_t)(b * NH_ + h) * S_ * HD_;
  Kb[t * 128 + d] = kv;
  Vb[t * 128 + d] = vv;
  qs[d] = qv;
  __syncthreads();

  int wave = d >> 6, lane = d & 63;
  for (int s = wave; s <= t; s += 2) {
    float pr = qs[lane] * Kb[s * 128 + lane] + qs[lane + 64] * Kb[s * 128 + lane + 64];
#pragma unroll
    for (int off = 32; off > 0; off >>= 1) pr += __shfl_down(pr, off, 64);
    if (lane == 0) sc[s] = pr * scale;
  }
  __syncthreads();

  float m = -3.4e38f;
  for (int s = 0; s <= t; ++s) m = fmaxf(m, sc[s]);
  float den = 0.f;
  for (int s = 0; s <= t; ++s) den += expf(sc[s] - m);
  float acc = 0.f;
  for (int s = 0; s <= t; ++s) acc += expf(sc[s] - m) * Vb[s * 128 + d];
  ctx[(size_t)b * 1024 + h * 128 + d] = acc / den;
}

// ---------------------------------------------------------------------------
__device__ __forceinline__ void ins3(float v, int i,
    float& v0, int& i0, float& v1, int& i1, float& v2, int& i2)
{
  if (v > v0 || (v == v0 && i < i0)) {
    v2 = v1; i2 = i1; v1 = v0; i1 = i0; v0 = v; i0 = i;
  } else if (v > v1 || (v == v1 && i < i1)) {
    v2 = v1; i2 = i1; v1 = v; i1 = i;
  } else if (v > v2 || (v == v2 && i < i2)) {
    v2 = v; i2 = i;
  }
}

// ---------------------------------------------------------------------------
// logits with fused qt-partial reduce AND per-block top3 candidates.
// 256 blocks x 512 thr; b = bid>>2, 128 n per block. Writes logits to d_out
// (write-only), candidates (top3 of this block's 128 n) to ws.
// ---------------------------------------------------------------------------
__global__ __launch_bounds__(512) void logits_fused(
    const float* __restrict__ P, const float* __restrict__ bc,
    const float* __restrict__ enc, float* __restrict__ out,
    float* __restrict__ candv, int* __restrict__ candi)
{
  __shared__ float qs[1024];
  __shared__ float sl[128];
  __shared__ float cv[48];
  __shared__ int   ci[48];
  int tid = threadIdx.x;
  int b = blockIdx.x >> 2, ng = blockIdx.x & 3;
  for (int i = tid; i < 1024; i += 512) {
    float s = bc[i];
#pragma unroll
    for (int sp = 0; sp < 16; ++sp) s += P[((size_t)sp * 64 + b) * 1024 + i];
    qs[i] = s;
  }
  __syncthreads();
  int wave = tid >> 6, lane = tid & 63;
  for (int j = 0; j < 16; ++j) {
    int ln = wave * 16 + j;
    const float* e = enc + ((size_t)b * N_ + ng * 128 + ln) * 1024;
    float pr = 0.f;
#pragma unroll
    for (int i = 0; i < 16; ++i) pr = fmaf(qs[lane + 64 * i], e[lane + 64 * i], pr);
#pragma unroll
    for (int off = 32; off > 0; off >>= 1) pr += __shfl_down(pr, off, 64);
    if (lane == 0) sl[ln] = pr;
  }
  __syncthreads();
  // coalesced logits store (d_out is write-only everywhere)
  if (tid < 128) out[(size_t)b * N_ + ng * 128 + tid] = sl[tid];
  // block-local top3: 16 lanes x 8-entry chunks (ascending n preserves ties)
  if (tid < 16) {
    float v0 = -3.4e38f, v1 = -3.4e38f, v2 = -3.4e38f;
    int i0 = 0x7fffffff, i1 = 0x7fffffff, i2 = 0x7fffffff;
    for (int k = 0; k < 8; ++k) {
      int ln = tid * 8 + k;
      ins3(sl[ln], ng * 128 + ln, v0, i0, v1, i1, v2, i2);
    }
    cv[tid * 3 + 0] = v0; ci[tid * 3 + 0] = i0;
    cv[tid * 3 + 1] = v1; ci[tid * 3 + 1] = i1;
    cv[tid * 3 + 2] = v2; ci[tid * 3 + 2] = i2;
  }
  __syncthreads();
  if (tid == 0) {
    float v0 = -3.4e38f, v1 = -3.4e38f, v2 = -3.4e38f;
    int i0 = 0x7fffffff, i1 = 0x7fffffff, i2 = 0x7fffffff;
    for (int k = 0; k < 48; ++k) ins3(cv[k], ci[k], v0, i0, v1, i1, v2, i2);
    candv[blockIdx.x * 3 + 0] = v0; candi[blockIdx.x * 3 + 0] = i0;
    candv[blockIdx.x * 3 + 1] = v1; candi[blockIdx.x * 3 + 1] = i1;
    candv[blockIdx.x * 3 + 2] = v2; candi[blockIdx.x * 3 + 2] = i2;
  }
}

// ---------------------------------------------------------------------------
// Merge 4 blocks' candidates per b -> final top3, sorted ascending.
// 1 block x 64 threads; reads only ws, writes idxi (ws) + idx (d_out).
// ---------------------------------------------------------------------------
__global__ __launch_bounds__(64) void top3_merge(
    const float* __restrict__ candv, const int* __restrict__ candi,
    float* __restrict__ idx_out, int* __restrict__ idxi)
{
  int b = threadIdx.x;
  float v0 = -3.4e38f, v1 = -3.4e38f, v2 = -3.4e38f;
  int i0 = 0x7fffffff, i1 = 0x7fffffff, i2 = 0x7fffffff;
#pragma unroll
  for (int q = 0; q < 4; ++q) {
    int base = (b * 4 + q) * 3;
#pragma unroll
    for (int k = 0; k < 3; ++k)
      ins3(candv[base + k], candi[base + k], v0, i0, v1, i1, v2, i2);
  }
  int a = i0, bb = i1, c = i2, tw;
  if (a > bb) { tw = a; a = bb; bb = tw; }
  if (bb > c) { tw = bb; bb = c; c = tw; }
  if (a > bb) { tw = a; a = bb; bb = tw; }
  idxi[b * 3 + 0] = a; idxi[b * 3 + 1] = bb; idxi[b * 3 + 2] = c;
  idx_out[b * 3 + 0] = (float)a;
  idx_out[b * 3 + 1] = (float)bb;
  idx_out[b * 3 + 2] = (float)c;
}

// ---------------------------------------------------------------------------
extern "C" void kernel_launch(void* const* d_in, const int* in_sizes, int n_in,
                              void* d_out, int out_size, void* d_ws, size_t ws_size,
                              hipStream_t stream)
{
  (void)in_sizes; (void)n_in; (void)out_size; (void)ws_size;
  const float* enc   = (const float*)d_in[0];
  const float* h0    = (const float*)d_in[1];
  const float* c0    = (const float*)d_in[2];
  const float* x0    = (const float*)d_in[4];
  const float* W_ih  = (const float*)d_in[6];
  const float* b_ih  = (const float*)d_in[7];
  const float* W_hh  = (const float*)d_in[8];
  const float* b_hh  = (const float*)d_in[9];
  const float* Wqkv  = (const float*)d_in[10];
  const float* bqkv  = (const float*)d_in[11];
  const float* Wout  = (const float*)d_in[12];
  const float* bout  = (const float*)d_in[13];
  const float* Wqt   = (const float*)d_in[14];
  const float* bqt   = (const float*)d_in[15];

  float* ws   = (float*)d_ws;
  float* P    = ws;                          // 8*64*4096 = 2.097M floats max
  float* W2   = P + 8 * 64 * 4096;           // 1024*2048
  float* bc   = W2 + 1024 * 2048;            // 1024
  float* hbuf = bc + 1024;                   // 64*1024
  float* cbuf = hbuf + 64 * 1024;
  float* ctx  = cbuf + 64 * 1024;
  float* Kc   = ctx + 64 * 1024;             // 64*8*24*128
  float* Vc   = Kc + 64 * NH_ * S_ * HD_;
  float* candv = Vc + 64 * NH_ * S_ * HD_;   // 256*3
  int*   candi = (int*)(candv + 768);        // 256*3
  int*   idxi  = candi + 768;                // 192

  float* logits_out = (float*)d_out;                     // [S,B,N]
  float* idx_out    = logits_out + (size_t)S_ * B_ * N_; // [S,B,3] as float

  // once per launch: combined qt weights/bias (step-invariant)
  wc_pre<<<dim3(256), dim3(256), 0, stream>>>(Wqt, Wout, W2);
  bc_pre<<<dim3(256), dim3(256), 0, stream>>>(Wqt, bout, bqt, bc);

  for (int t = 0; t < S_; ++t) {
    const float* xin   = (t == 0) ? x0 : nullptr;   // t>0: gather from enc
    const float* hprev = (t == 0) ? h0 : hbuf;
    const float* cprev = (t == 0) ? c0 : cbuf;

    // gates = [x|h] @ [W_ih|W_hh]^T -> P[8][64][4096]
    gemm5<<<dim3(32, 8), dim3(512), 0, stream>>>(
        xin, 3072, W_ih, 3072, 3072,
        hprev, 1024, W_hh, 1024,
        enc, idxi, t > 0, P, 4096, 512);
    lstm_red<<<dim3(64), dim3(256), 0, stream>>>(P, b_ih, b_hh, cprev, hbuf, cbuf);

    // qkv = h @ Wqkv^T -> P[8][64][3072]
    gemm5<<<dim3(24, 8), dim3(512), 0, stream>>>(
        hbuf, 1024, Wqkv, 1024, 1024,
        hbuf, 1024, Wqkv, 1024,
        enc, idxi, 0, P, 3072, 128);
    attn_fused<<<dim3(512), dim3(128), 0, stream>>>(P, bqkv, Kc, Vc, ctx, t);

    // query = [h|ctx] @ W2^T (+bc at reduce) -> P[16][64][1024]
    gemm5<<<dim3(8, 16), dim3(512), 0, stream>>>(
        hbuf, 1024, W2, 2048, 1024,
        ctx, 1024, W2 + 1024, 2048,
        enc, idxi, 0, P, 1024, 128);
    logits_fused<<<dim3(256), dim3(512), 0, stream>>>(
        P, bc, enc, logits_out + (size_t)t * B_ * N_, candv, candi);
    top3_merge<<<dim3(1), dim3(64), 0, stream>>>(
        candv, candi, idx_out + (size_t)t * B_ * 3, idxi);
  }
}